// Round 3
// baseline (472.344 us; speedup 1.0000x reference)
//
#include <hip/hip_runtime.h>
#include <math.h>

#define B_N   8
#define CIN   512
#define COUT  64
#define HW    4096
#define ALPHA 8.3f

#define TR 4          // tile rows per block
#define TC 32         // tile cols per block
#define NSTEP 8       // 256 ch per k-half / 32 ch per step
#define PITCH 40      // LDS ch pitch (elems): 80 B lane stride, 16B-aligned b128
#define BUFELEM (6*34*PITCH)   // 8160 elems = 16320 B per (pipe,kh) buffer

typedef short v8s  __attribute__((ext_vector_type(8)));
typedef float v16f __attribute__((ext_vector_type(16)));
typedef float v4f  __attribute__((ext_vector_type(4)));

static __device__ __forceinline__ unsigned short f2bf(float f) {
    unsigned int u = __float_as_uint(f);
    u = (u + 0x7fffu + ((u >> 16) & 1u)) >> 16;   // RNE
    return (unsigned short)u;
}

// A-fragment pre-swizzle (verified in R2):
// wt[((tap*32 + ks)*2 + mt)*64 + lane][8] ; o = mt*32+(lane&31), c = ks*16+(lane>>5)*8+j
__global__ void prep_weights(const float* __restrict__ w, unsigned short* __restrict__ wt) {
    int i = blockIdx.x * 256 + threadIdx.x;
    if (i >= 9 * 32 * 2 * 64 * 8) return;
    int j    = i & 7;
    int lane = (i >> 3) & 63;
    int mt   = (i >> 9) & 1;
    int ks   = (i >> 10) & 31;
    int tap  = i >> 15;
    int o = mt * 32 + (lane & 31);
    int c = ks * 16 + (lane >> 5) * 8 + j;
    wt[i] = f2bf(w[(o * CIN + c) * 9 + tap]);
}

__global__ __launch_bounds__(512, 2)
void depthconv_mfma2(const float* __restrict__ x,
                     const float* __restrict__ depth,
                     const unsigned short* __restrict__ wt,
                     float* __restrict__ out) {
    __shared__ unsigned short xs[4 * BUFELEM];   // 65,280 B: 2 pipes x 2 kh

    // XCD-swizzled decode: xcd gets ht pair {2x,2x+1} for all (b,wtile) -> halo L2 reuse
    const int bx    = blockIdx.x;
    const int xcd   = bx & 7;
    const int i0    = bx >> 3;
    const int wtile = i0 & 1;
    const int b     = (i0 >> 1) & 7;
    const int ht    = xcd * 2 + (i0 >> 4);
    const int h0 = ht * TR, w0 = wtile * TC;

    const int tid  = threadIdx.x;
    const int wid  = tid >> 6;
    const int lane = tid & 63;
    const int l31  = lane & 31;
    const int half = lane >> 5;
    const int s    = wid & 3;    // row slot: output row h0+s
    const int kh   = wid >> 2;   // k-half: channels [kh*256, kh*256+256)

    // ---- gates (OOB depth = 0, matches jnp.pad; verified R2) ----
    float g[9];
    {
        const float* dp = depth + (size_t)b * HW;
        const int hq = h0 + s, wq = w0 + l31;
        const float d0 = dp[hq * 64 + wq];
#pragma unroll
        for (int t = 0; t < 9; ++t) {
            const int hn = hq + t / 3 - 1, wn = wq + t % 3 - 1;
            const float dn = (hn >= 0 && hn < 64 && wn >= 0 && wn < 64) ? dp[hn * 64 + wn] : 0.f;
            g[t] = __expf(-ALPHA * fabsf(d0 - dn));
        }
    }

    v16f acc[2];
    v16f vzero;
#pragma unroll
    for (int r = 0; r < 16; ++r) { acc[0][r] = 0.f; acc[1][r] = 0.f; vzero[r] = 0.f; }

    const float* xg = x + (size_t)b * CIN * HW;

    // staging prefetch state: 3264 groups (2 kh x 6 r x 34 c x 8 chg) / 512 thr -> 7 iters
    float pv[7][4];
    int   lofs[7];

#define LOAD_STEP(STP)                                                          \
    {                                                                           \
        const int st_ = (STP);                                                  \
        _Pragma("unroll")                                                       \
        for (int k = 0; k < 7; ++k) {                                           \
            const int i = tid + k * 512;                                        \
            lofs[k] = -1;                                                       \
            if (i < 3264) {                                                     \
                const int c   = i % 34;                                         \
                const int t   = i / 34;                                         \
                const int chg = t & 7;                                          \
                const int t2  = t >> 3;                                         \
                const int r   = t2 % 6;                                         \
                const int khs = t2 / 6;                                         \
                const int hh = h0 - 1 + r, ww = w0 - 1 + c;                     \
                const int ch = khs * 256 + st_ * 32 + chg * 4;                  \
                lofs[k] = ((st_ & 1) * 2 + khs) * BUFELEM                       \
                        + (r * 34 + c) * PITCH + chg * 4;                       \
                const bool ok = (hh >= 0 && hh < 64 && ww >= 0 && ww < 64);     \
                const float* p = xg + (size_t)ch * HW + hh * 64 + ww;           \
                _Pragma("unroll")                                               \
                for (int j = 0; j < 4; ++j) pv[k][j] = ok ? p[(size_t)j * HW] : 0.f; \
            }                                                                   \
        }                                                                       \
    }

#define WRITE_STEP()                                                            \
    {                                                                           \
        _Pragma("unroll")                                                       \
        for (int k = 0; k < 7; ++k) {                                           \
            if (lofs[k] >= 0) {                                                 \
                const unsigned int lo = (unsigned)f2bf(pv[k][0]) | ((unsigned)f2bf(pv[k][1]) << 16); \
                const unsigned int hi = (unsigned)f2bf(pv[k][2]) | ((unsigned)f2bf(pv[k][3]) << 16); \
                uint2 u; u.x = lo; u.y = hi;                                    \
                *(uint2*)&xs[lofs[k]] = u;                                      \
            }                                                                   \
        }                                                                       \
    }

    LOAD_STEP(0);
    WRITE_STEP();

    for (int st = 0; st < NSTEP; ++st) {
        __syncthreads();                       // buffer pipe (st&1) ready
        if (st < NSTEP - 1) LOAD_STEP(st + 1); // global loads fly during compute
        const int base = ((st & 1) * 2 + kh) * BUFELEM;
#pragma unroll
        for (int tap = 0; tap < 9; ++tap) {
            const int di = tap / 3, dj = tap % 3;
            const int rr = s + di, cc = l31 + dj;
            v8s bfr[2];
#pragma unroll
            for (int kk = 0; kk < 2; ++kk)
                bfr[kk] = *(const v8s*)&xs[base + (rr * 34 + cc) * PITCH + kk * 16 + half * 8];
            v8s afr[2][2];
#pragma unroll
            for (int kk = 0; kk < 2; ++kk) {
                const int ks = kh * 16 + st * 2 + kk;
#pragma unroll
                for (int mt = 0; mt < 2; ++mt)
                    afr[kk][mt] = *(const v8s*)&wt[(((tap * 32 + ks) * 2 + mt) * 64 + lane) * 8];
            }
#pragma unroll
            for (int mt = 0; mt < 2; ++mt) {
                v16f pass = __builtin_amdgcn_mfma_f32_32x32x16_bf16(afr[0][mt], bfr[0], vzero, 0, 0, 0);
                pass = __builtin_amdgcn_mfma_f32_32x32x16_bf16(afr[1][mt], bfr[1], pass, 0, 0, 0);
                const float gv = g[tap];
#pragma unroll
                for (int r = 0; r < 16; ++r)
                    acc[mt][r] = fmaf(gv, pass[r], acc[mt][r]);
            }
        }
        if (st < NSTEP - 1) WRITE_STEP();      // into pipe (st+1)&1; barrier above fenced step st-1 readers
    }

    // ---- in-block K-half reduction via LDS, then direct coalesced stores ----
    __syncthreads();
    float* red = (float*)xs;
    if (kh == 1) {
#pragma unroll
        for (int mt = 0; mt < 2; ++mt)
#pragma unroll
            for (int q = 0; q < 4; ++q) {
                v4f v; v[0] = acc[mt][q*4]; v[1] = acc[mt][q*4+1];
                v[2] = acc[mt][q*4+2]; v[3] = acc[mt][q*4+3];
                *(v4f*)&red[s * 2048 + mt * 1024 + lane * 16 + q * 4] = v;
            }
    }
    __syncthreads();
    if (kh == 0) {
        float* ob = out + (size_t)b * COUT * HW + (h0 + s) * 64 + w0;
#pragma unroll
        for (int mt = 0; mt < 2; ++mt)
#pragma unroll
            for (int q = 0; q < 4; ++q) {
                const v4f v = *(const v4f*)&red[s * 2048 + mt * 1024 + lane * 16 + q * 4];
#pragma unroll
                for (int j = 0; j < 4; ++j) {
                    const int rg = q * 4 + j;
                    const int o = mt * 32 + (rg & 3) + 8 * (rg >> 2) + 4 * half;
                    ob[(size_t)o * HW + l31] = acc[mt][rg] + v[j];
                }
            }
    }
}

extern "C" void kernel_launch(void* const* d_in, const int* in_sizes, int n_in,
                              void* d_out, int out_size, void* d_ws, size_t ws_size,
                              hipStream_t stream) {
    const float* x      = (const float*)d_in[0];
    const float* depth  = (const float*)d_in[1];
    const float* weight = (const float*)d_in[2];
    float* out = (float*)d_out;
    unsigned short* wt = (unsigned short*)d_ws;   // 589,824 B frag-major bf16 weights

    prep_weights<<<1152, 256, 0, stream>>>(weight, wt);
    depthconv_mfma2<<<256, 512, 0, stream>>>(x, depth, wt, out);
}

// Round 4
// 251.886 us; speedup vs baseline: 1.8752x; 1.8752x over previous
//
#include <hip/hip_runtime.h>
#include <math.h>

#define ALPHA 8.3f

typedef short v8s  __attribute__((ext_vector_type(8)));
typedef float v16f __attribute__((ext_vector_type(16)));
typedef float v4f  __attribute__((ext_vector_type(4)));

static __device__ __forceinline__ unsigned short f2bf(float f) {
    unsigned int u = __float_as_uint(f);
    u = (u + 0x7fffu + ((u >> 16) & 1u)) >> 16;   // RNE
    return (unsigned short)u;
}

// A-fragment pre-swizzle (verified R2/R3):
// wt[((tap*32 + ks)*2 + mt)*64 + lane][8] ; o = mt*32+(lane&31), c = ks*16+(lane>>5)*8+j
__global__ void prep_weights(const float* __restrict__ w, unsigned short* __restrict__ wt) {
    int i = blockIdx.x * 256 + threadIdx.x;
    if (i >= 9 * 32 * 2 * 64 * 8) return;
    int j    = i & 7;
    int lane = (i >> 3) & 63;
    int mt   = (i >> 9) & 1;
    int ks   = (i >> 10) & 31;
    int tap  = i >> 15;
    int o = mt * 32 + (lane & 31);
    int c = ks * 16 + (lane >> 5) * 8 + j;
    wt[i] = f2bf(w[(o * 512 + c) * 9 + tap]);
}

// x fp32 NCHW -> bf16 NHWC  (x2[b][h][w][c], 512 B... 512 ushort per pixel)
__global__ __launch_bounds__(256) void nhwc_cast(const float* __restrict__ x,
                                                 unsigned short* __restrict__ x2) {
    __shared__ float st[64][65];
    const int h = blockIdx.x & 63;
    const int b = blockIdx.x >> 6;
    const int tid = threadIdx.x;
    const float* xb = x + ((size_t)b * 512) * 4096 + h * 64;
    unsigned short* ob = x2 + (((size_t)b * 64 + h) * 64) * 512;
    for (int cb = 0; cb < 8; ++cb) {
        __syncthreads();
#pragma unroll
        for (int i = 0; i < 16; ++i) {
            const int c = i * 4 + (tid >> 6);
            st[c][tid & 63] = xb[(size_t)(cb * 64 + c) * 4096 + (tid & 63)];
        }
        __syncthreads();
#pragma unroll
        for (int j = 0; j < 2; ++j) {
            const int idx = j * 256 + tid;
            const int w = idx >> 3, k = idx & 7;
            unsigned short t[8];
#pragma unroll
            for (int e = 0; e < 8; ++e) t[e] = f2bf(st[k * 8 + e][w]);
            uint4 u;
            u.x = t[0] | ((unsigned)t[1] << 16);
            u.y = t[2] | ((unsigned)t[3] << 16);
            u.z = t[4] | ((unsigned)t[5] << 16);
            u.w = t[6] | ((unsigned)t[7] << 16);
            *(uint4*)&ob[(size_t)w * 512 + cb * 64 + k * 8] = u;
        }
    }
}

// Main: 512 blocks x 256 thr. Block = (b, 2 rows, 32 cols), 4 waves = 4 kh
// quarters (128 ch each). Wave tile M=64 x N=64 (2mt x 2nt rows).
// 4 supersteps x 32 ch/quarter staged in LDS (bf16, XOR-swizzled granules).
__global__ __launch_bounds__(256, 2)
void depthconv_v4(const unsigned short* __restrict__ x2,
                  const float* __restrict__ depth,
                  const unsigned short* __restrict__ wt,
                  float* __restrict__ out) {
    __shared__ __align__(16) char smem[65536];           // union: x-stage 34.8 KB / red 64 KB
    unsigned short* xs = (unsigned short*)smem;
    float* red = (float*)smem;

    const int bx  = blockIdx.x;
    const int wt2 = bx & 1;
    const int ht  = (bx >> 1) & 31;
    const int b   = bx >> 6;
    const int h0 = ht * 2, w0 = wt2 * 32;

    const int tid  = threadIdx.x;
    const int q    = tid >> 6;        // kh quarter 0..3
    const int lane = tid & 63;
    const int l31  = lane & 31;
    const int half = lane >> 5;

    // ---- gates (fp32, OOB depth = 0; verified R2) ----
    float gt[2][9];
    {
        const float* dp = depth + (size_t)b * 4096;
#pragma unroll
        for (int nt = 0; nt < 2; ++nt) {
            const int hq = h0 + nt, wq = w0 + l31;
            const float d0 = dp[hq * 64 + wq];
#pragma unroll
            for (int t = 0; t < 9; ++t) {
                const int hn = hq + t / 3 - 1, wn = wq + t % 3 - 1;
                const float dn = (hn >= 0 && hn < 64 && wn >= 0 && wn < 64) ? dp[hn * 64 + wn] : 0.f;
                gt[nt][t] = __expf(-ALPHA * fabsf(d0 - dn));
            }
        }
    }

    v16f acc[2][2];
    v16f vzero;
#pragma unroll
    for (int r = 0; r < 16; ++r) {
        acc[0][0][r] = 0.f; acc[0][1][r] = 0.f; acc[1][0][r] = 0.f; acc[1][1][r] = 0.f;
        vzero[r] = 0.f;
    }

    const unsigned short* xpix = x2 + ((size_t)b * 4096) * 512;   // + (h*64+w)*512

    for (int ss = 0; ss < 4; ++ss) {
        __syncthreads();
        // ---- stage: 136 slices (4r x 34c) x 16 granules of 16 B (256 ch = 4q x 32) ----
        for (int it = 0; it < 9; ++it) {
            const int i = it * 256 + tid;
            if (i < 2176) {
                const int k     = i & 15;
                const int slice = i >> 4;
                const int r = slice / 34;
                const int c = slice - r * 34;
                const int hh = h0 - 1 + r, ww = w0 - 1 + c;
                uint4 v = make_uint4(0, 0, 0, 0);
                if (hh >= 0 && hh < 64 && ww >= 0 && ww < 64) {
                    const int q2 = k >> 2;
                    const int kg = q2 * 16 + ss * 4 + (k & 3);   // global 16B chunk (8 ch)
                    v = *(const uint4*)&xpix[((size_t)(hh * 64 + ww)) * 512 + kg * 8];
                }
                const int p = (k & 8) | ((k ^ c) & 7);           // XOR bank swizzle
                *(uint4*)&xs[slice * 128 + p * 8] = v;
            }
        }
        __syncthreads();

#pragma unroll
        for (int tap = 0; tap < 9; ++tap) {
            const int di = tap / 3, dj = tap % 3;
            v8s a[2][2];   // [kk][mt]
#pragma unroll
            for (int kk = 0; kk < 2; ++kk) {
                const int ks = q * 8 + ss * 2 + kk;
#pragma unroll
                for (int mt = 0; mt < 2; ++mt)
                    a[kk][mt] = *(const v8s*)&wt[(((tap * 32 + ks) * 2 + mt) * 64 + lane) * 8];
            }
            v8s bf[2][2];  // [kk][nt]
#pragma unroll
            for (int kk = 0; kk < 2; ++kk)
#pragma unroll
                for (int nt = 0; nt < 2; ++nt) {
                    const int c = l31 + dj;
                    const int slice = (nt + di) * 34 + c;
                    const int g = q * 4 + kk * 2 + half;
                    const int p = (g & 8) | ((g ^ c) & 7);
                    bf[kk][nt] = *(const v8s*)&xs[slice * 128 + p * 8];
                }
#pragma unroll
            for (int mt = 0; mt < 2; ++mt)
#pragma unroll
                for (int nt = 0; nt < 2; ++nt) {
                    v16f pass = __builtin_amdgcn_mfma_f32_32x32x16_bf16(a[0][mt], bf[0][nt], vzero, 0, 0, 0);
                    pass = __builtin_amdgcn_mfma_f32_32x32x16_bf16(a[1][mt], bf[1][nt], pass, 0, 0, 0);
                    const float gv = gt[nt][tap];
#pragma unroll
                    for (int r = 0; r < 16; ++r)
                        acc[mt][nt][r] = fmaf(gv, pass[r], acc[mt][nt][r]);
                }
        }
    }

    // ---- epilogue: 4-way in-block reduction, out written exactly once ----
    __syncthreads();
#pragma unroll
    for (int mt = 0; mt < 2; ++mt)
#pragma unroll
        for (int nt = 0; nt < 2; ++nt) {
            const int combo = mt * 2 + nt;
#pragma unroll
            for (int qd = 0; qd < 4; ++qd) {
                v4f v;
                v[0] = acc[mt][nt][qd * 4];     v[1] = acc[mt][nt][qd * 4 + 1];
                v[2] = acc[mt][nt][qd * 4 + 2]; v[3] = acc[mt][nt][qd * 4 + 3];
                *(v4f*)&red[(((combo * 4 + qd) * 4 + q) * 64 + lane) * 4] = v;
            }
        }
    __syncthreads();
    {
        const int mt = q >> 1, nt = q & 1;
#pragma unroll
        for (int qd = 0; qd < 4; ++qd) {
            v4f s = *(const v4f*)&red[(((q * 4 + qd) * 4 + 0) * 64 + lane) * 4];
#pragma unroll
            for (int w = 1; w < 4; ++w) {
                const v4f t = *(const v4f*)&red[(((q * 4 + qd) * 4 + w) * 64 + lane) * 4];
                s[0] += t[0]; s[1] += t[1]; s[2] += t[2]; s[3] += t[3];
            }
#pragma unroll
            for (int j = 0; j < 4; ++j) {
                const int rg = qd * 4 + j;
                const int o = mt * 32 + (rg & 3) + 8 * (rg >> 2) + 4 * half;   // verified C-layout
                out[(((size_t)b * 64 + o) * 64 + h0 + nt) * 64 + w0 + l31] = s[j];
            }
        }
    }
}

extern "C" void kernel_launch(void* const* d_in, const int* in_sizes, int n_in,
                              void* d_out, int out_size, void* d_ws, size_t ws_size,
                              hipStream_t stream) {
    const float* x      = (const float*)d_in[0];
    const float* depth  = (const float*)d_in[1];
    const float* weight = (const float*)d_in[2];
    float* out = (float*)d_out;

    unsigned short* wtb = (unsigned short*)d_ws;                       // 589,824 B
    unsigned short* x2  = (unsigned short*)((char*)d_ws + (1 << 20));  // 33.6 MB bf16 NHWC

    prep_weights<<<1152, 256, 0, stream>>>(weight, wtb);
    nhwc_cast<<<512, 256, 0, stream>>>(x, x2);
    depthconv_v4<<<512, 256, 0, stream>>>(x2, depth, wtb, out);
}

// Round 5
// 147.425 us; speedup vs baseline: 3.2040x; 1.7086x over previous
//
#include <hip/hip_runtime.h>
#include <math.h>

#define ALPHA 8.3f
#define STAGE_BYTES 26112    // 1632 granules * 16 B (6 rows x 34 cols x 8 granules)

typedef short v8s  __attribute__((ext_vector_type(8)));
typedef float v16f __attribute__((ext_vector_type(16)));
typedef float v4f  __attribute__((ext_vector_type(4)));

static __device__ __forceinline__ unsigned short f2bf(float f) {
    unsigned int u = __float_as_uint(f);
    u = (u + 0x7fffu + ((u >> 16) & 1u)) >> 16;   // RNE
    return (unsigned short)u;
}

static __device__ __forceinline__ void async16(const void* g, void* l) {
    __builtin_amdgcn_global_load_lds(
        (const __attribute__((address_space(1))) unsigned int*)g,
        (__attribute__((address_space(3))) unsigned int*)l, 16, 0, 0);
}

// A-fragment pre-swizzle (verified R2-R4):
// wt[((tap*32 + ks)*2 + mt)*64 + lane][8] ; o = mt*32+(lane&31), c = ks*16+(lane>>5)*8+j
__global__ void prep_weights(const float* __restrict__ w, unsigned short* __restrict__ wt) {
    int i = blockIdx.x * 256 + threadIdx.x;
    if (i >= 9 * 32 * 2 * 64 * 8) return;
    int j    = i & 7;
    int lane = (i >> 3) & 63;
    int mt   = (i >> 9) & 1;
    int ks   = (i >> 10) & 31;
    int tap  = i >> 15;
    int o = mt * 32 + (lane & 31);
    int c = ks * 16 + (lane >> 5) * 8 + j;
    wt[i] = f2bf(w[(o * 512 + c) * 9 + tap]);
}

// x fp32 NCHW -> bf16 NHWC (x2[b][h][w][c]) — unchanged from R4
__global__ __launch_bounds__(256) void nhwc_cast(const float* __restrict__ x,
                                                 unsigned short* __restrict__ x2) {
    __shared__ float st[64][65];
    const int h = blockIdx.x & 63;
    const int b = blockIdx.x >> 6;
    const int tid = threadIdx.x;
    const float* xb = x + ((size_t)b * 512) * 4096 + h * 64;
    unsigned short* ob = x2 + (((size_t)b * 64 + h) * 64) * 512;
    for (int cb = 0; cb < 8; ++cb) {
        __syncthreads();
#pragma unroll
        for (int i = 0; i < 16; ++i) {
            const int c = i * 4 + (tid >> 6);
            st[c][tid & 63] = xb[(size_t)(cb * 64 + c) * 4096 + (tid & 63)];
        }
        __syncthreads();
#pragma unroll
        for (int j = 0; j < 2; ++j) {
            const int idx = j * 256 + tid;
            const int w = idx >> 3, k = idx & 7;
            unsigned short t[8];
#pragma unroll
            for (int e = 0; e < 8; ++e) t[e] = f2bf(st[k * 8 + e][w]);
            uint4 u;
            u.x = t[0] | ((unsigned)t[1] << 16);
            u.y = t[2] | ((unsigned)t[3] << 16);
            u.z = t[4] | ((unsigned)t[5] << 16);
            u.w = t[6] | ((unsigned)t[7] << 16);
            *(uint4*)&ob[(size_t)w * 512 + cb * 64 + k * 8] = u;
        }
    }
}

// Main: 256 blocks (1/CU) x 512 thr. Block = (b, 4 rows, 32 cols), all 64 Cout.
// 8 waves = kh(2) x mt(2) x rt(2). Wave: M=32 (mt), 2 rows (rt) x 32 cols, K=256 (kh).
// 8 supersteps x 64 ch (32/kh) DMA-staged via global_load_lds, double-buffered.
__global__ __launch_bounds__(512, 2)
void depthconv_v5(const unsigned short* __restrict__ x2,
                  const float* __restrict__ depth,
                  const unsigned short* __restrict__ wt,
                  const float* __restrict__ zbuf,
                  float* __restrict__ out) {
    __shared__ __align__(16) char smem[2 * STAGE_BYTES];   // 52,224 B (epilogue reuses)

    // XCD-swizzled decode: xcd owns rows [xcd*8, xcd*8+8) for all (b, wtile)
    const int bx   = blockIdx.x;
    const int xcd  = bx & 7;
    const int i0   = bx >> 3;          // 0..31
    const int wt2  = i0 & 1;
    const int b    = (i0 >> 1) & 7;
    const int ht   = xcd * 2 + (i0 >> 4);
    const int h0 = ht * 4, w0 = wt2 * 32;

    const int tid  = threadIdx.x;
    const int wid  = tid >> 6;
    const int lane = tid & 63;
    const int l31  = lane & 31;
    const int half = lane >> 5;
    const int mt   = wid & 1;
    const int rt   = (wid >> 1) & 1;
    const int kh   = wid >> 2;

    const char* xpix = (const char*)(x2 + ((size_t)b * 4096) * 512);

    // ---- gates for my 2 rows (fp32, OOB depth = 0; verified R2) ----
    float gt[2][9];
    {
        const float* dp = depth + (size_t)b * 4096;
#pragma unroll
        for (int nt = 0; nt < 2; ++nt) {
            const int hq = h0 + 2 * rt + nt, wq = w0 + l31;
            const float d0 = dp[hq * 64 + wq];
#pragma unroll
            for (int t = 0; t < 9; ++t) {
                const int hn = hq + t / 3 - 1, wn = wq + t % 3 - 1;
                const float dn = (hn >= 0 && hn < 64 && wn >= 0 && wn < 64) ? dp[hn * 64 + wn] : 0.f;
                gt[nt][t] = __expf(-ALPHA * fabsf(d0 - dn));
            }
        }
    }

    v16f acc[2];
    v16f vzero;
#pragma unroll
    for (int r = 0; r < 16; ++r) { acc[0][r] = 0.f; acc[1][r] = 0.f; vzero[r] = 0.f; }

    // granule i (0..1631): slice = i>>3 (r*34+c, rows h0-1..h0+4, cols w0-1..w0+32),
    // gg = (i&7)^(slice&7); content = ch [(gg>>2)*256 + ss*32 + (gg&3)*8, +8).
    // LDS lane-linear (DMA), reads land conflict-free via the i-space XOR.
#define ISSUE(SS)                                                               \
    {                                                                           \
        const int ss_ = (SS);                                                   \
        char* bufb = smem + (ss_ & 1) * STAGE_BYTES;                            \
        _Pragma("unroll")                                                       \
        for (int it = 0; it < 4; ++it) {                                        \
            const int i = it * 512 + tid;                                       \
            if (i < 1632) {                                                     \
                const int slice = i >> 3;                                       \
                const int gg = (i & 7) ^ (slice & 7);                           \
                const int r = slice / 34;                                       \
                const int c = slice - r * 34;                                   \
                const int hh = h0 - 1 + r, ww = w0 - 1 + c;                     \
                const char* gp = (hh >= 0 && hh < 64 && ww >= 0 && ww < 64)     \
                    ? xpix + (size_t)(hh * 64 + ww) * 1024                      \
                           + (gg >> 2) * 512 + ss_ * 64 + (gg & 3) * 16        \
                    : (const char*)zbuf;                                        \
                async16(gp, bufb + it * 8192 + wid * 1024 + lane * 16);         \
            }                                                                   \
        }                                                                       \
    }

    ISSUE(0);

    for (int ss = 0; ss < 8; ++ss) {
        __syncthreads();                    // drains DMA(ss) (vmcnt0) + fences prev compute
        if (ss < 7) ISSUE(ss + 1);          // DMA(ss+1) flies under compute(ss)
        const char* bufb = smem + (ss & 1) * STAGE_BYTES;
        const int ks0 = kh * 16 + ss * 2;
#pragma unroll
        for (int tap = 0; tap < 9; ++tap) {
            const int di = tap / 3, dj = tap % 3;
            const v8s a0 = *(const v8s*)&wt[(((tap * 32 + ks0) * 2 + mt) * 64 + lane) * 8];
            const v8s a1 = *(const v8s*)&wt[(((tap * 32 + ks0 + 1) * 2 + mt) * 64 + lane) * 8];
#pragma unroll
            for (int nt = 0; nt < 2; ++nt) {
                const int slice = (2 * rt + nt + di) * 34 + l31 + dj;
                const int s7 = slice & 7;
                const int g0 = kh * 4 + half;        // kk=0
                const int g1 = g0 + 2;               // kk=1
                const v8s b0 = *(const v8s*)(bufb + ((size_t)(slice * 8 + (g0 ^ s7))) * 16);
                const v8s b1 = *(const v8s*)(bufb + ((size_t)(slice * 8 + (g1 ^ s7))) * 16);
                v16f pass = __builtin_amdgcn_mfma_f32_32x32x16_bf16(a0, b0, vzero, 0, 0, 0);
                pass = __builtin_amdgcn_mfma_f32_32x32x16_bf16(a1, b1, pass, 0, 0, 0);
                const float gv = gt[nt][tap];
#pragma unroll
                for (int r = 0; r < 16; ++r)
                    acc[nt][r] = fmaf(gv, pass[r], acc[nt][r]);
            }
        }
    }

    // ---- in-block kh reduction (LDS reuses stage buffers), out written once ----
    __syncthreads();
    float* red = (float*)smem;
    const int region = mt * 2 + rt;
    if (kh == 1) {
#pragma unroll
        for (int nt = 0; nt < 2; ++nt)
#pragma unroll
            for (int qd = 0; qd < 4; ++qd) {
                v4f v;
                v[0] = acc[nt][qd * 4];     v[1] = acc[nt][qd * 4 + 1];
                v[2] = acc[nt][qd * 4 + 2]; v[3] = acc[nt][qd * 4 + 3];
                *(v4f*)&red[(region * 2 + nt) * 1024 + lane * 16 + qd * 4] = v;
            }
    }
    __syncthreads();
    if (kh == 0) {
#pragma unroll
        for (int nt = 0; nt < 2; ++nt) {
            float* ob = out + ((size_t)b * 64) * 4096 + (h0 + 2 * rt + nt) * 64 + w0;
#pragma unroll
            for (int qd = 0; qd < 4; ++qd) {
                const v4f v = *(const v4f*)&red[(region * 2 + nt) * 1024 + lane * 16 + qd * 4];
#pragma unroll
                for (int j = 0; j < 4; ++j) {
                    const int rg = qd * 4 + j;
                    const int o = mt * 32 + (rg & 3) + 8 * (rg >> 2) + 4 * half;  // verified C-layout
                    ob[(size_t)o * 4096 + l31] = acc[nt][rg] + v[j];
                }
            }
        }
    }
}

extern "C" void kernel_launch(void* const* d_in, const int* in_sizes, int n_in,
                              void* d_out, int out_size, void* d_ws, size_t ws_size,
                              hipStream_t stream) {
    const float* x      = (const float*)d_in[0];
    const float* depth  = (const float*)d_in[1];
    const float* weight = (const float*)d_in[2];
    float* out = (float*)d_out;

    unsigned short* wtb = (unsigned short*)d_ws;                        // 589,824 B
    float* zbuf         = (float*)((char*)d_ws + 786432);               // 1 KB zeros (halo)
    unsigned short* x2  = (unsigned short*)((char*)d_ws + (1 << 20));   // 33.6 MB bf16 NHWC

    prep_weights<<<1152, 256, 0, stream>>>(weight, wtb);
    hipMemsetAsync(zbuf, 0, 1024, stream);   // d_ws is re-poisoned 0xAA every launch
    nhwc_cast<<<512, 256, 0, stream>>>(x, x2);
    depthconv_v5<<<256, 512, 0, stream>>>(x2, depth, wtb, zbuf, out);
}